// Round 7
// baseline (124.430 us; speedup 1.0000x reference)
//
#include <hip/hip_runtime.h>
#include <hip/hip_bf16.h>

#define B_ 8
#define Q_ 128
#define K_ 256
#define D_ 512
#define TWOLOG2E 2.8853900817779268f
#define SCALE 0.044194173824159216f   // 1/sqrt(512)
#define L2E 1.4426950408889634f
#define MASKVAL (-44194173.824159216f) // -1e9 * SCALE

typedef __attribute__((ext_vector_type(8))) short frag8;   // 8 bf16
typedef __attribute__((ext_vector_type(4))) float f32x4;

__device__ __forceinline__ float fexp2(float x) {
  float r;
  asm("v_exp_f32 %0, %1" : "=v"(r) : "v"(x));
  return r;
}
__device__ __forceinline__ float frcp(float x) {
  float r;
  asm("v_rcp_f32 %0, %1" : "=v"(r) : "v"(x));
  return r;
}
__device__ __forceinline__ unsigned f2bf_u(float x) {
  unsigned u = __float_as_uint(x);
  return (u + 0x7FFFu + ((u >> 16) & 1u)) >> 16;
}
__device__ __forceinline__ unsigned short f2bf(float x) {
  return (unsigned short)f2bf_u(x);
}
__device__ __forceinline__ unsigned packbf(float lo, float hi) {
  return f2bf_u(lo) | (f2bf_u(hi) << 16);
}

// ---------------- Kernel 1: fused convert + MFMA projection GEMM ----------------
// (unchanged from R6)
__global__ __launch_bounds__(256) void gemm_kernel(
    const float* __restrict__ query, const float* __restrict__ key,
    const float* __restrict__ W1, const float* __restrict__ b1,
    float* __restrict__ qp, float* __restrict__ kpbT) {
  __shared__ short As[32 * 64];
  __shared__ short Bs[64 * 72];
  const int t = threadIdx.x;
  const int m0 = blockIdx.y * 32;
  const int n0 = blockIdx.x * 64;
  const bool is_k = (m0 >= B_ * Q_);
  const float* X = is_k ? key : query;
  const int xrow0 = is_k ? (m0 - B_ * Q_) : m0;
  const float* Wb = W1 + (is_k ? (size_t)D_ * D_ : 0);

  const int am = t >> 3;
  const int ac = t & 7;
  const float* gA = X + (size_t)(xrow0 + am) * D_ + ac * 8;
  short* aw = As + am * 64 + ((ac ^ (am & 7)) * 8);

  const int prow = t >> 4;
  const int n4 = (t & 15) * 4;
  const float* gB = Wb + n0 + n4;

  const int l = t & 63;
  const int w = t >> 6;
  const int lr = l & 15;
  const int kg = l >> 4;
  const int key8 = lr & 7;
  int aoff[2][2], boff[2];
#pragma unroll
  for (int kk = 0; kk < 2; ++kk) {
    const int cposA = ((kg + kk * 4) ^ key8) * 8;
#pragma unroll
    for (int mt = 0; mt < 2; ++mt) aoff[mt][kk] = (mt * 16 + lr) * 64 + cposA;
    boff[kk] = (w * 16 + lr) * 72 + (kg + kk * 4) * 8;
  }

  f32x4 acc[2];
  acc[0] = (f32x4){0.f, 0.f, 0.f, 0.f};
  acc[1] = (f32x4){0.f, 0.f, 0.f, 0.f};

  for (int k0 = 0; k0 < D_; k0 += 64) {
    float4 a0 = *(const float4*)(gA + k0);
    float4 a1 = *(const float4*)(gA + k0 + 4);
    float4 w00 = *(const float4*)(gB + (size_t)(k0 + 2 * prow) * D_);
    float4 w01 = *(const float4*)(gB + (size_t)(k0 + 2 * prow + 1) * D_);
    float4 w10 = *(const float4*)(gB + (size_t)(k0 + 2 * prow + 32) * D_);
    float4 w11 = *(const float4*)(gB + (size_t)(k0 + 2 * prow + 33) * D_);
    __syncthreads();
    {
      union { frag8 f; unsigned short u[8]; } av;
      av.u[0] = f2bf(a0.x); av.u[1] = f2bf(a0.y); av.u[2] = f2bf(a0.z); av.u[3] = f2bf(a0.w);
      av.u[4] = f2bf(a1.x); av.u[5] = f2bf(a1.y); av.u[6] = f2bf(a1.z); av.u[7] = f2bf(a1.w);
      *(frag8*)aw = av.f;
    }
    {
      float lo0[4] = {w00.x, w00.y, w00.z, w00.w};
      float hi0[4] = {w01.x, w01.y, w01.z, w01.w};
      float lo1[4] = {w10.x, w10.y, w10.z, w10.w};
      float hi1[4] = {w11.x, w11.y, w11.z, w11.w};
#pragma unroll
      for (int j = 0; j < 4; ++j) {
        *(unsigned*)(Bs + (n4 + j) * 72 + 2 * prow) = packbf(lo0[j], hi0[j]);
        *(unsigned*)(Bs + (n4 + j) * 72 + 2 * (prow + 16)) = packbf(lo1[j], hi1[j]);
      }
    }
    __syncthreads();
#pragma unroll
    for (int kk = 0; kk < 2; ++kk) {
      frag8 bf = *(const frag8*)(Bs + boff[kk]);
#pragma unroll
      for (int mt = 0; mt < 2; ++mt) {
        frag8 af = *(const frag8*)(As + aoff[mt][kk]);
        acc[mt] = __builtin_amdgcn_mfma_f32_16x16x32_bf16(af, bf, acc[mt], 0, 0, 0);
      }
    }
  }

  const int col = n0 + w * 16 + lr;
  if (is_k) {
    const float bc = b1[col];
#pragma unroll
    for (int mt = 0; mt < 2; ++mt) {
      const int krow = m0 - B_ * Q_ + mt * 16 + kg * 4;
      const int bb = krow >> 8;
      const int kk0 = krow & 255;
      float4 v;
      v.x = fexp2((acc[mt][0] + bc) * TWOLOG2E);
      v.y = fexp2((acc[mt][1] + bc) * TWOLOG2E);
      v.z = fexp2((acc[mt][2] + bc) * TWOLOG2E);
      v.w = fexp2((acc[mt][3] + bc) * TWOLOG2E);
      *(float4*)&kpbT[((size_t)bb * D_ + col) * K_ + kk0] = v;
    }
  } else {
#pragma unroll
    for (int mt = 0; mt < 2; ++mt) {
#pragma unroll
      for (int i = 0; i < 4; ++i) {
        const int row = m0 + mt * 16 + kg * 4 + i;
        qp[(size_t)row * D_ + col] = fexp2(acc[mt][i] * TWOLOG2E);
      }
    }
  }
}

// ---------------- Kernel 2: masked-compacted tanh-score + softmax + PV ----------------
// qp holds Eq = e^{2 qproj}; kpbT holds Ek = e^{2(kproj+b1)}.
// 1024 threads = 16 waves, 2 q-rows/block, grid (64, 8) = 512 blocks (2/CU).
// Phase 0: wave 0 ballot-compacts unmasked k (M of 256).
// Phase 1: kchunks = 2^ceil-ish(M/64); wave w: kc = w&(kchunks-1) compacted
//          k-chunk, h-chunk = (w>>s) of length 32<<s. Per elem: fma+rcp+fma.
__global__ __launch_bounds__(1024, 8) void attn_kernel(
    const float* __restrict__ qp, const float* __restrict__ kpbT,
    const float* __restrict__ value, const int* __restrict__ mask,
    const float* __restrict__ w2,
    float* __restrict__ out_vec, float* __restrict__ out_w) {
  __shared__ int idxl[K_];
  __shared__ int sM;
  __shared__ float smem_p[16 * 2 * 64];  // [w][q][lane]
  __shared__ float pw[2 * K_];           // scores then weights: [q][k]
  const int b = blockIdx.y;
  const int q0 = blockIdx.x * 2;
  const int t = threadIdx.x;
  const int lane = t & 63;
  const int w = __builtin_amdgcn_readfirstlane(t >> 6);  // 0..15

  // ---- phase 0: compaction (wave 0)
  if (w == 0) {
    int base = 0;
#pragma unroll
    for (int c = 0; c < 4; ++c) {
      const int k = c * 64 + lane;
      const int mk = mask[b * K_ + k];
      const unsigned long long bal = __ballot(mk == 0);
      const int pos = __popcll(bal & ((1ull << lane) - 1ull));
      if (mk == 0) idxl[base + pos] = k;
      base += (int)__popcll(bal);
    }
    if (lane == 0) sM = base;
  }
  __syncthreads();

  const int M = sM;
  const int s = (M > 128) ? 2 : (M > 64) ? 1 : 0;
  const int kchunks = 1 << s;

  // ---- phase 1
  {
    const int kc = w & (kchunks - 1);
    const int hsel = w >> s;
    const int hlen = 32 << s;
    const int h0 = hsel * hlen;

    const int slot = kc * 64 + lane;
    const int sl = (slot < M) ? slot : (M > 0 ? M - 1 : 0);
    const int kk = idxl[sl] & 255;

    const float* pk = kpbT + ((size_t)b * D_ + h0) * K_ + kk;
    const float* q_0 = qp + (size_t)(b * Q_ + q0 + 0) * D_ + h0;
    const float* q_1 = qp + (size_t)(b * Q_ + q0 + 1) * D_ + h0;
    const float* w2h = w2 + h0;

    float a0 = 0.f, a1 = 0.f;
    for (int h = 0; h < hlen; h += 8) {
      float kv[8];
#pragma unroll
      for (int j = 0; j < 8; ++j) kv[j] = pk[(size_t)(h + j) * K_];
      float4 e0a = *(const float4*)(q_0 + h), e0b = *(const float4*)(q_0 + h + 4);
      float4 e1a = *(const float4*)(q_1 + h), e1b = *(const float4*)(q_1 + h + 4);
      float4 wa = *(const float4*)(w2h + h), wb = *(const float4*)(w2h + h + 4);
      float E0[8] = {e0a.x, e0a.y, e0a.z, e0a.w, e0b.x, e0b.y, e0b.z, e0b.w};
      float E1[8] = {e1a.x, e1a.y, e1a.z, e1a.w, e1b.x, e1b.y, e1b.z, e1b.w};
      float WV[8] = {wa.x, wa.y, wa.z, wa.w, wb.x, wb.y, wb.z, wb.w};
#pragma unroll
      for (int j = 0; j < 8; ++j) {
        const float r0 = frcp(fmaf(E0[j], kv[j], 1.f));
        const float r1 = frcp(fmaf(E1[j], kv[j], 1.f));
        a0 = fmaf(WV[j], r0, a0);
        a1 = fmaf(WV[j], r1, a1);
      }
    }
    smem_p[w * 128 + 0 * 64 + lane] = a0;
    smem_p[w * 128 + 1 * 64 + lane] = a1;
  }
  __syncthreads();

  // ---- phase 2: combine + scatter + softmax (wave q = 0,1)
  if (w < 2) {
    const int q = w;
    float sw = 0.f;
#pragma unroll
    for (int m = 0; m < 8; ++m) sw += w2[lane + 64 * m];
#pragma unroll
    for (int off = 32; off; off >>= 1) sw += __shfl_xor(sw, off);

    // init all scores to MASKVAL
#pragma unroll
    for (int r = 0; r < 4; ++r) pw[q * K_ + r * 64 + lane] = MASKVAL;
    // combine partials and scatter to original k positions
    for (int r = 0; r < kchunks; ++r) {
      float p = 0.f;
      for (int v = 0; v < (16 >> s); ++v)
        p += smem_p[(((v << s) | r) * 2 + q) * 64 + lane];
      const int slot = r * 64 + lane;
      if (slot < M) pw[q * K_ + idxl[slot]] = fmaf(-2.f, p, sw) * SCALE;
    }

    float sv[4];
#pragma unroll
    for (int r = 0; r < 4; ++r) sv[r] = pw[q * K_ + r * 64 + lane];
    float mx = fmaxf(fmaxf(sv[0], sv[1]), fmaxf(sv[2], sv[3]));
#pragma unroll
    for (int off = 32; off; off >>= 1) mx = fmaxf(mx, __shfl_xor(mx, off));
    float e[4], sum = 0.f;
#pragma unroll
    for (int r = 0; r < 4; ++r) {
      e[r] = fexp2((sv[r] - mx) * L2E);
      sum += e[r];
    }
#pragma unroll
    for (int off = 32; off; off >>= 1) sum += __shfl_xor(sum, off);
    const float inv = frcp(sum);
    float* ow = out_w + (size_t)(b * Q_ + q0 + q) * K_;
#pragma unroll
    for (int r = 0; r < 4; ++r) {
      const float p = e[r] * inv;
      pw[q * K_ + r * 64 + lane] = p;
      ow[r * 64 + lane] = p;
    }
  }
  __syncthreads();

  // ---- phase 3: PV. thread t -> col = t&511, q = t>>9
  const int col = t & 511;
  const int qq = t >> 9;
  float o = 0.f;
  const float* vb = value + (size_t)b * K_ * D_;
  for (int k = 0; k < K_; k += 4) {
    const float4 p = *(const float4*)&pw[qq * K_ + k];
    const float v0 = vb[(size_t)(k + 0) * D_ + col];
    const float v1 = vb[(size_t)(k + 1) * D_ + col];
    const float v2 = vb[(size_t)(k + 2) * D_ + col];
    const float v3 = vb[(size_t)(k + 3) * D_ + col];
    o = fmaf(p.x, v0, fmaf(p.y, v1, fmaf(p.z, v2, fmaf(p.w, v3, o))));
  }
  out_vec[(size_t)(b * Q_ + q0 + qq) * D_ + col] = o;
}

extern "C" void kernel_launch(void* const* d_in, const int* in_sizes, int n_in,
                              void* d_out, int out_size, void* d_ws, size_t ws_size,
                              hipStream_t stream) {
  const float* query = (const float*)d_in[0];
  const float* key   = (const float*)d_in[1];
  const float* value = (const float*)d_in[2];
  const int*   mask  = (const int*)d_in[3];
  const float* W1    = (const float*)d_in[4];
  const float* b1    = (const float*)d_in[5];
  const float* w2    = (const float*)d_in[6];

  float* out_vec = (float*)d_out;                   // (8,128,512)
  float* out_w   = out_vec + (size_t)B_ * Q_ * D_;  // (8,128,256)

  float* qp   = (float*)d_ws;                       // 2 MB fp32 Eq [b][q][h]
  float* kpbT = qp + (size_t)B_ * Q_ * D_;          // 4 MB fp32 Ek [b][h][k]

  gemm_kernel<<<dim3(8, 96), 256, 0, stream>>>(query, key, W1, b1, qp, kpbT);
  attn_kernel<<<dim3(Q_ / 2, B_), 1024, 0, stream>>>(qp, kpbT, value, mask, w2,
                                                     out_vec, out_w);
}

// Round 8
// 111.611 us; speedup vs baseline: 1.1149x; 1.1149x over previous
//
#include <hip/hip_runtime.h>
#include <hip/hip_bf16.h>

#define B_ 8
#define Q_ 128
#define K_ 256
#define D_ 512
#define TWOLOG2E 2.8853900817779268f
#define SCALE 0.044194173824159216f   // 1/sqrt(512)
#define L2E 1.4426950408889634f
#define MASKVAL (-44194173.824159216f) // -1e9 * SCALE

typedef __attribute__((ext_vector_type(8))) short frag8;   // 8 bf16
typedef __attribute__((ext_vector_type(4))) float f32x4;

__device__ __forceinline__ float fexp2(float x) {
  float r;
  asm("v_exp_f32 %0, %1" : "=v"(r) : "v"(x));
  return r;
}
__device__ __forceinline__ float frcp(float x) {
  float r;
  asm("v_rcp_f32 %0, %1" : "=v"(r) : "v"(x));
  return r;
}
__device__ __forceinline__ unsigned f2bf_u(float x) {
  unsigned u = __float_as_uint(x);
  return (u + 0x7FFFu + ((u >> 16) & 1u)) >> 16;
}
__device__ __forceinline__ unsigned short f2bf(float x) {
  return (unsigned short)f2bf_u(x);
}
__device__ __forceinline__ unsigned packbf(float lo, float hi) {
  return f2bf_u(lo) | (f2bf_u(hi) << 16);
}

// ---------------- Kernel 1: fused convert + MFMA projection GEMM ----------------
// (unchanged from R6)
__global__ __launch_bounds__(256) void gemm_kernel(
    const float* __restrict__ query, const float* __restrict__ key,
    const float* __restrict__ W1, const float* __restrict__ b1,
    float* __restrict__ qp, float* __restrict__ kpbT) {
  __shared__ short As[32 * 64];
  __shared__ short Bs[64 * 72];
  const int t = threadIdx.x;
  const int m0 = blockIdx.y * 32;
  const int n0 = blockIdx.x * 64;
  const bool is_k = (m0 >= B_ * Q_);
  const float* X = is_k ? key : query;
  const int xrow0 = is_k ? (m0 - B_ * Q_) : m0;
  const float* Wb = W1 + (is_k ? (size_t)D_ * D_ : 0);

  const int am = t >> 3;
  const int ac = t & 7;
  const float* gA = X + (size_t)(xrow0 + am) * D_ + ac * 8;
  short* aw = As + am * 64 + ((ac ^ (am & 7)) * 8);

  const int prow = t >> 4;
  const int n4 = (t & 15) * 4;
  const float* gB = Wb + n0 + n4;

  const int l = t & 63;
  const int w = t >> 6;
  const int lr = l & 15;
  const int kg = l >> 4;
  const int key8 = lr & 7;
  int aoff[2][2], boff[2];
#pragma unroll
  for (int kk = 0; kk < 2; ++kk) {
    const int cposA = ((kg + kk * 4) ^ key8) * 8;
#pragma unroll
    for (int mt = 0; mt < 2; ++mt) aoff[mt][kk] = (mt * 16 + lr) * 64 + cposA;
    boff[kk] = (w * 16 + lr) * 72 + (kg + kk * 4) * 8;
  }

  f32x4 acc[2];
  acc[0] = (f32x4){0.f, 0.f, 0.f, 0.f};
  acc[1] = (f32x4){0.f, 0.f, 0.f, 0.f};

  for (int k0 = 0; k0 < D_; k0 += 64) {
    float4 a0 = *(const float4*)(gA + k0);
    float4 a1 = *(const float4*)(gA + k0 + 4);
    float4 w00 = *(const float4*)(gB + (size_t)(k0 + 2 * prow) * D_);
    float4 w01 = *(const float4*)(gB + (size_t)(k0 + 2 * prow + 1) * D_);
    float4 w10 = *(const float4*)(gB + (size_t)(k0 + 2 * prow + 32) * D_);
    float4 w11 = *(const float4*)(gB + (size_t)(k0 + 2 * prow + 33) * D_);
    __syncthreads();
    {
      union { frag8 f; unsigned short u[8]; } av;
      av.u[0] = f2bf(a0.x); av.u[1] = f2bf(a0.y); av.u[2] = f2bf(a0.z); av.u[3] = f2bf(a0.w);
      av.u[4] = f2bf(a1.x); av.u[5] = f2bf(a1.y); av.u[6] = f2bf(a1.z); av.u[7] = f2bf(a1.w);
      *(frag8*)aw = av.f;
    }
    {
      float lo0[4] = {w00.x, w00.y, w00.z, w00.w};
      float hi0[4] = {w01.x, w01.y, w01.z, w01.w};
      float lo1[4] = {w10.x, w10.y, w10.z, w10.w};
      float hi1[4] = {w11.x, w11.y, w11.z, w11.w};
#pragma unroll
      for (int j = 0; j < 4; ++j) {
        *(unsigned*)(Bs + (n4 + j) * 72 + 2 * prow) = packbf(lo0[j], hi0[j]);
        *(unsigned*)(Bs + (n4 + j) * 72 + 2 * (prow + 16)) = packbf(lo1[j], hi1[j]);
      }
    }
    __syncthreads();
#pragma unroll
    for (int kk = 0; kk < 2; ++kk) {
      frag8 bf = *(const frag8*)(Bs + boff[kk]);
#pragma unroll
      for (int mt = 0; mt < 2; ++mt) {
        frag8 af = *(const frag8*)(As + aoff[mt][kk]);
        acc[mt] = __builtin_amdgcn_mfma_f32_16x16x32_bf16(af, bf, acc[mt], 0, 0, 0);
      }
    }
  }

  const int col = n0 + w * 16 + lr;
  if (is_k) {
    const float bc = b1[col];
#pragma unroll
    for (int mt = 0; mt < 2; ++mt) {
      const int krow = m0 - B_ * Q_ + mt * 16 + kg * 4;
      const int bb = krow >> 8;
      const int kk0 = krow & 255;
      float4 v;
      v.x = fexp2((acc[mt][0] + bc) * TWOLOG2E);
      v.y = fexp2((acc[mt][1] + bc) * TWOLOG2E);
      v.z = fexp2((acc[mt][2] + bc) * TWOLOG2E);
      v.w = fexp2((acc[mt][3] + bc) * TWOLOG2E);
      *(float4*)&kpbT[((size_t)bb * D_ + col) * K_ + kk0] = v;
    }
  } else {
#pragma unroll
    for (int mt = 0; mt < 2; ++mt) {
#pragma unroll
      for (int i = 0; i < 4; ++i) {
        const int row = m0 + mt * 16 + kg * 4 + i;
        qp[(size_t)row * D_ + col] = fexp2(acc[mt][i] * TWOLOG2E);
      }
    }
  }
}

// ---------------- Kernel 2: fused tanh-score + softmax + PV ----------------
// qp holds Eq = e^{2 qproj}; kpbT holds Ek = e^{2(kproj+b1)}.
// 1024 threads = 16 waves, 4 q-rows/block, grid (32, 8) = 256 blocks.
// Wave w: kc = w&1 -> k-range kc*128 + 2*lane (2 k/lane, float2 loads);
//         hq = w>>1 -> h-range hq*64. Per elem: fma + rcp + fma.
__global__ __launch_bounds__(1024) void attn_kernel(
    const float* __restrict__ qp, const float* __restrict__ kpbT,
    const float* __restrict__ value, const int* __restrict__ mask,
    const float* __restrict__ w2,
    float* __restrict__ out_vec, float* __restrict__ out_w) {
  __shared__ float smem_p[16 * 512];  // [w][q(4)][128 k-pos]  32 KB
  __shared__ float pw[4 * 256];       // final weights [q][k]   4 KB
  const int b = blockIdx.y;
  const int q0 = blockIdx.x * 4;
  const int t = threadIdx.x;
  const int lane = t & 63;
  const int w = __builtin_amdgcn_readfirstlane(t >> 6);  // 0..15
  const int kc = w & 1;
  const int hq = w >> 1;
  const int h0 = hq * 64;

  // ---- phase 1: partials over this wave's (128 k, 64 h)
  {
    const float* pk = kpbT + ((size_t)b * D_ + h0) * K_ + kc * 128 + 2 * lane;
    const float* q_0 = qp + (size_t)(b * Q_ + q0 + 0) * D_ + h0;
    const float* q_1 = qp + (size_t)(b * Q_ + q0 + 1) * D_ + h0;
    const float* q_2 = qp + (size_t)(b * Q_ + q0 + 2) * D_ + h0;
    const float* q_3 = qp + (size_t)(b * Q_ + q0 + 3) * D_ + h0;
    const float* w2h = w2 + h0;

    float2 a0 = {0.f, 0.f}, a1 = {0.f, 0.f}, a2 = {0.f, 0.f}, a3 = {0.f, 0.f};
    for (int h = 0; h < 64; h += 8) {
      float2 kv[8];
#pragma unroll
      for (int j = 0; j < 8; ++j) kv[j] = *(const float2*)&pk[(size_t)(h + j) * K_];
      float4 e0a = *(const float4*)(q_0 + h), e0b = *(const float4*)(q_0 + h + 4);
      float4 e1a = *(const float4*)(q_1 + h), e1b = *(const float4*)(q_1 + h + 4);
      float4 e2a = *(const float4*)(q_2 + h), e2b = *(const float4*)(q_2 + h + 4);
      float4 e3a = *(const float4*)(q_3 + h), e3b = *(const float4*)(q_3 + h + 4);
      float4 wa = *(const float4*)(w2h + h), wb = *(const float4*)(w2h + h + 4);
      float E0[8] = {e0a.x, e0a.y, e0a.z, e0a.w, e0b.x, e0b.y, e0b.z, e0b.w};
      float E1[8] = {e1a.x, e1a.y, e1a.z, e1a.w, e1b.x, e1b.y, e1b.z, e1b.w};
      float E2[8] = {e2a.x, e2a.y, e2a.z, e2a.w, e2b.x, e2b.y, e2b.z, e2b.w};
      float E3[8] = {e3a.x, e3a.y, e3a.z, e3a.w, e3b.x, e3b.y, e3b.z, e3b.w};
      float WV[8] = {wa.x, wa.y, wa.z, wa.w, wb.x, wb.y, wb.z, wb.w};
#pragma unroll
      for (int j = 0; j < 8; ++j) {
        a0.x = fmaf(WV[j], frcp(fmaf(E0[j], kv[j].x, 1.f)), a0.x);
        a0.y = fmaf(WV[j], frcp(fmaf(E0[j], kv[j].y, 1.f)), a0.y);
        a1.x = fmaf(WV[j], frcp(fmaf(E1[j], kv[j].x, 1.f)), a1.x);
        a1.y = fmaf(WV[j], frcp(fmaf(E1[j], kv[j].y, 1.f)), a1.y);
        a2.x = fmaf(WV[j], frcp(fmaf(E2[j], kv[j].x, 1.f)), a2.x);
        a2.y = fmaf(WV[j], frcp(fmaf(E2[j], kv[j].y, 1.f)), a2.y);
        a3.x = fmaf(WV[j], frcp(fmaf(E3[j], kv[j].x, 1.f)), a3.x);
        a3.y = fmaf(WV[j], frcp(fmaf(E3[j], kv[j].y, 1.f)), a3.y);
      }
    }
    *(float2*)&smem_p[w * 512 + 0 * 128 + 2 * lane] = a0;
    *(float2*)&smem_p[w * 512 + 1 * 128 + 2 * lane] = a1;
    *(float2*)&smem_p[w * 512 + 2 * 128 + 2 * lane] = a2;
    *(float2*)&smem_p[w * 512 + 3 * 128 + 2 * lane] = a3;
  }
  __syncthreads();

  // ---- phase 2: combine + softmax; wave q (0..3) handles row q0+q
  if (w < 4) {
    const int q = w;
    float sw = 0.f;
#pragma unroll
    for (int m = 0; m < 8; ++m) sw += w2[lane + 64 * m];
#pragma unroll
    for (int off = 32; off; off >>= 1) sw += __shfl_xor(sw, off);

    float s[4];
#pragma unroll
    for (int r = 0; r < 4; ++r) {  // k = r*64 + lane
      const int kcc = r >> 1;
      const int off = (r & 1) * 64 + lane;  // position within kc's 128-range
      float p = 0.f;
#pragma unroll
      for (int hh = 0; hh < 8; ++hh)
        p += smem_p[(hh * 2 + kcc) * 512 + q * 128 + off];
      const int mk = mask[b * K_ + r * 64 + lane];
      s[r] = mk ? MASKVAL : fmaf(-2.f, p, sw) * SCALE;
    }
    float mx = fmaxf(fmaxf(s[0], s[1]), fmaxf(s[2], s[3]));
#pragma unroll
    for (int off = 32; off; off >>= 1) mx = fmaxf(mx, __shfl_xor(mx, off));
    float e[4], sum = 0.f;
#pragma unroll
    for (int r = 0; r < 4; ++r) {
      e[r] = fexp2((s[r] - mx) * L2E);
      sum += e[r];
    }
#pragma unroll
    for (int off = 32; off; off >>= 1) sum += __shfl_xor(sum, off);
    const float inv = frcp(sum);
    float* ow = out_w + (size_t)(b * Q_ + q0 + q) * K_;
#pragma unroll
    for (int r = 0; r < 4; ++r) {
      const float p = e[r] * inv;
      pw[q * 256 + r * 64 + lane] = p;
      ow[r * 64 + lane] = p;
    }
  }
  __syncthreads();

  // ---- phase 3: PV. thread t -> col = t&511, q-pair qq = t>>9
  const int col = t & 511;
  const int qq = t >> 9;
  float o0 = 0.f, o1 = 0.f;
  const float* vb = value + (size_t)b * K_ * D_;
  for (int k = 0; k < K_; k += 4) {
    const float4 p0 = *(const float4*)&pw[(qq * 2 + 0) * 256 + k];
    const float4 p1 = *(const float4*)&pw[(qq * 2 + 1) * 256 + k];
    const float v0 = vb[(size_t)(k + 0) * D_ + col];
    const float v1 = vb[(size_t)(k + 1) * D_ + col];
    const float v2 = vb[(size_t)(k + 2) * D_ + col];
    const float v3 = vb[(size_t)(k + 3) * D_ + col];
    o0 = fmaf(p0.x, v0, fmaf(p0.y, v1, fmaf(p0.z, v2, fmaf(p0.w, v3, o0))));
    o1 = fmaf(p1.x, v0, fmaf(p1.y, v1, fmaf(p1.z, v2, fmaf(p1.w, v3, o1))));
  }
  out_vec[(size_t)(b * Q_ + q0 + qq * 2 + 0) * D_ + col] = o0;
  out_vec[(size_t)(b * Q_ + q0 + qq * 2 + 1) * D_ + col] = o1;
}

extern "C" void kernel_launch(void* const* d_in, const int* in_sizes, int n_in,
                              void* d_out, int out_size, void* d_ws, size_t ws_size,
                              hipStream_t stream) {
  const float* query = (const float*)d_in[0];
  const float* key   = (const float*)d_in[1];
  const float* value = (const float*)d_in[2];
  const int*   mask  = (const int*)d_in[3];
  const float* W1    = (const float*)d_in[4];
  const float* b1    = (const float*)d_in[5];
  const float* w2    = (const float*)d_in[6];

  float* out_vec = (float*)d_out;                   // (8,128,512)
  float* out_w   = out_vec + (size_t)B_ * Q_ * D_;  // (8,128,256)

  float* qp   = (float*)d_ws;                       // 2 MB fp32 Eq [b][q][h]
  float* kpbT = qp + (size_t)B_ * Q_ * D_;          // 4 MB fp32 Ek [b][h][k]

  gemm_kernel<<<dim3(8, 96), 256, 0, stream>>>(query, key, W1, b1, qp, kpbT);
  attn_kernel<<<dim3(Q_ / 4, B_), 1024, 0, stream>>>(qp, kpbT, value, mask, w2,
                                                     out_vec, out_w);
}